// Round 1
// baseline (1215.071 us; speedup 1.0000x reference)
//
#include <hip/hip_runtime.h>
#include <cstdint>
#include <cstddef>

// ---------------------------------------------------------------------------
// Problem constants
// ---------------------------------------------------------------------------
#define B_SZ   2
#define T_SEQ  4096
#define DIM_   2048
#define NH_    16
#define HD_    128          // head dim
#define QKVD   (3*DIM_)     // 6144

typedef __bf16 bf16x4 __attribute__((ext_vector_type(4)));
typedef __bf16 bf16x8 __attribute__((ext_vector_type(8)));
typedef float  f32x4  __attribute__((ext_vector_type(4)));

typedef const __attribute__((address_space(1))) void* gas_ptr_t;
typedef       __attribute__((address_space(3))) void* las_ptr_t;

#define GLOAD_LDS16(gp, lp) \
  __builtin_amdgcn_global_load_lds((gas_ptr_t)(gp), (las_ptr_t)(lp), 16, 0, 0)

// ---------------------------------------------------------------------------
// fp32 -> bf16 cast (vectorized, memory bound)
// ---------------------------------------------------------------------------
__global__ void cast_f32_bf16(const float* __restrict__ in,
                              __bf16* __restrict__ out, int n4) {
  int i = blockIdx.x * blockDim.x + threadIdx.x;
  if (i < n4) {
    float4 v = ((const float4*)in)[i];
    bf16x4 o = { (__bf16)v.x, (__bf16)v.y, (__bf16)v.z, (__bf16)v.w };
    ((bf16x4*)out)[i] = o;
  }
}

// ---------------------------------------------------------------------------
// bf16 GEMM, C[m][n] = sum_k A[m][k] * B[n][k]   (B is row-major [N][K], i.e. B^T)
// m97 pattern: 128x128 tile, BK=32, global_load_lds width 16, 16x16x32 MFMA.
// Verified layouts: A-frag A[m=lane&15][k=quad*8+j]; B-frag B[n=lane&15][k=quad*8+j];
// C/D: col=lane&15, row=quad*4+reg.
// ---------------------------------------------------------------------------
__device__ __forceinline__ void store_c(float* C, size_t idx, float v)  { C[idx] = v; }
__device__ __forceinline__ void store_c(__bf16* C, size_t idx, float v) { C[idx] = (__bf16)v; }

template <typename OutT>
__global__ __launch_bounds__(256, 2) void gemm_bt(const __bf16* __restrict__ A,
                                                  const __bf16* __restrict__ B,
                                                  OutT* __restrict__ C,
                                                  int M, int N, int K) {
  __shared__ __attribute__((aligned(16))) __bf16 As[128 * 32];
  __shared__ __attribute__((aligned(16))) __bf16 Bs[128 * 32];

  const int tid  = threadIdx.x;
  const int wave = tid >> 6;
  const int lane = tid & 63;
  const int lrow = lane & 15;
  const int quad = lane >> 4;
  const int m0 = blockIdx.x * 128;
  const int n0 = blockIdx.y * 128;
  const int wm = (wave & 1) * 64;
  const int wn = (wave >> 1) * 64;

  // staging: thread covers row tid/4, 8-elem chunk tid%4 (rows 0..63); +64 on 2nd call
  const __bf16* Ag = A + (size_t)(m0 + (tid >> 2)) * K + (tid & 3) * 8;
  const __bf16* Bg = B + (size_t)(n0 + (tid >> 2)) * K + (tid & 3) * 8;

  f32x4 acc[4][4] = {};

  for (int k0 = 0; k0 < K; k0 += 32) {
    __syncthreads();
    GLOAD_LDS16(Ag + k0,                 &As[wave * 16 * 32]);
    GLOAD_LDS16(Ag + k0 + (size_t)64*K,  &As[(64 + wave * 16) * 32]);
    GLOAD_LDS16(Bg + k0,                 &Bs[wave * 16 * 32]);
    GLOAD_LDS16(Bg + k0 + (size_t)64*K,  &Bs[(64 + wave * 16) * 32]);
    __syncthreads();   // drains vmcnt before barrier (compiler-enforced)

    bf16x8 a[4], b[4];
#pragma unroll
    for (int i = 0; i < 4; i++)
      a[i] = *(const bf16x8*)&As[(wm + i * 16 + lrow) * 32 + quad * 8];
#pragma unroll
    for (int j = 0; j < 4; j++)
      b[j] = *(const bf16x8*)&Bs[(wn + j * 16 + lrow) * 32 + quad * 8];
#pragma unroll
    for (int i = 0; i < 4; i++)
#pragma unroll
      for (int j = 0; j < 4; j++)
        acc[i][j] = __builtin_amdgcn_mfma_f32_16x16x32_bf16(a[i], b[j], acc[i][j], 0, 0, 0);
  }

#pragma unroll
  for (int i = 0; i < 4; i++)
#pragma unroll
    for (int j = 0; j < 4; j++)
#pragma unroll
      for (int r = 0; r < 4; r++) {
        size_t row = (size_t)(m0 + wm + i * 16 + quad * 4 + r);
        size_t col = (size_t)(n0 + wn + j * 16 + lrow);
        store_c(C, row * (size_t)N + col, acc[i][j][r]);
      }
}

// ---------------------------------------------------------------------------
// RoPE + split heads.
// qkv: [B*T][6144] bf16 (q | k | v).  Writes:
//   Q,K: [bh][t][d] bf16, rope applied  (bh = b*16+h)
//   Vt : [bh][d][t] bf16 (transposed for PV B-fragment reads)
// Reference semantics: out[d] = x[d]*cos(t*f[d&63]) + rot[d]*sin(t*f[d&63]),
//   rot[2i] = -x[2i+1], rot[2i+1] = x[2i];  f[i] = 10000^(-i/64).
// ---------------------------------------------------------------------------
__global__ void rope_split(const __bf16* __restrict__ qkv,
                           __bf16* __restrict__ Qo,
                           __bf16* __restrict__ Ko,
                           __bf16* __restrict__ Vt) {
  const long id  = (long)blockIdx.x * blockDim.x + threadIdx.x;  // < 8192*3072
  const int row = (int)(id / 3072);      // b*T + t
  const int p   = (int)(id % 3072);
  const int b = row >> 12;
  const int t = row & (T_SEQ - 1);
  const __bf16* src = qkv + (size_t)row * QKVD;

  if (p < 2048) {                        // q or k pair
    const bool isq = (p < 1024);
    const int pp = isq ? p : p - 1024;
    const int dp = pp * 2;               // even element index in [0,2048)
    const int h = dp >> 7, d = dp & 127;
    const int base = isq ? 0 : DIM_;
    const float x0 = (float)src[base + dp];
    const float x1 = (float)src[base + dp + 1];
    const int i0 = d & 63, i1 = (d + 1) & 63;
    // inv_freq = 2^(-i/64 * log2(10000))
    const float kf = -0.20762050593049014f;   // -log2(10000)/64
    float a0 = (float)t * exp2f(i0 * kf);
    float a1 = (float)t * exp2f(i1 * kf);
    float s0, c0, s1, c1;
    sincosf(a0, &s0, &c0);
    sincosf(a1, &s1, &c1);
    float y0 = x0 * c0 - x1 * s0;
    float y1 = x1 * c1 + x0 * s1;
    __bf16* dst = (isq ? Qo : Ko) + (((size_t)(b * NH_ + h) * T_SEQ + t) * HD_ + d);
    dst[0] = (__bf16)y0;
    dst[1] = (__bf16)y1;
  } else {                               // v pair -> transposed store
    const int dp = (p - 2048) * 2;
    const int h = dp >> 7, d = dp & 127;
    __bf16 v0 = src[2 * DIM_ + dp];
    __bf16 v1 = src[2 * DIM_ + dp + 1];
    size_t base = (size_t)(b * NH_ + h) * HD_;
    Vt[(base + d)     * T_SEQ + t] = v0;
    Vt[(base + d + 1) * T_SEQ + t] = v1;
  }
}

// ---------------------------------------------------------------------------
// Flash attention (causal, online softmax).
// Grid: (T/64, B*NH). Block 256 = 4 waves; wave w owns q rows [qb*64+w*16, +16).
// K tile [64][128] LDS stride 136 (+8 pad -> 4-bank rotation/row, 2-way max).
// Vt tile [128][64] LDS stride 72.
// P round-trips C-layout -> A-layout through per-wave LDS.
// Output O: [b][t][h][d] bf16 (ready as GEMM A for projection).
// ---------------------------------------------------------------------------
__global__ __launch_bounds__(256, 2) void flash_attn(const __bf16* __restrict__ Q,
                                                     const __bf16* __restrict__ K,
                                                     const __bf16* __restrict__ Vt,
                                                     __bf16* __restrict__ O) {
  __shared__ __attribute__((aligned(16))) __bf16 Ks[64 * 136];
  __shared__ __attribute__((aligned(16))) __bf16 Vs[128 * 72];
  __shared__ __attribute__((aligned(16))) __bf16 Ps[4][16 * 72];

  const int qb   = (gridDim.x - 1) - blockIdx.x;  // big blocks dispatch first
  const int bh   = blockIdx.y;
  const int tid  = threadIdx.x;
  const int wave = tid >> 6;
  const int lane = tid & 63;
  const int lrow = lane & 15;
  const int quad = lane >> 4;

  const __bf16* Qh = Q  + (size_t)bh * T_SEQ * HD_;
  const __bf16* Kh = K  + (size_t)bh * T_SEQ * HD_;
  const __bf16* Vh = Vt + (size_t)bh * HD_ * T_SEQ;

  const int q0 = qb * 64 + wave * 16;

  bf16x8 qf[4];
#pragma unroll
  for (int c = 0; c < 4; c++)
    qf[c] = *(const bf16x8*)&Qh[(size_t)(q0 + lrow) * HD_ + c * 32 + quad * 8];

  f32x4 o[8] = {};
  float m_[4], l_[4];
#pragma unroll
  for (int r = 0; r < 4; r++) { m_[r] = -1e30f; l_[r] = 0.f; }

  for (int kb = 0; kb <= qb; ++kb) {
    __syncthreads();
    // stage K tile: 64 x 128
#pragma unroll
    for (int ro = 0; ro < 4; ro++) {
      int r = ro * 16 + (tid >> 4), cc = tid & 15;
      *(bf16x8*)&Ks[r * 136 + cc * 8] =
          *(const bf16x8*)&Kh[(size_t)(kb * 64 + r) * HD_ + cc * 8];
    }
    // stage Vt tile: 128 x 64
#pragma unroll
    for (int ro = 0; ro < 4; ro++) {
      int d = ro * 32 + (tid >> 3), cc = tid & 7;
      *(bf16x8*)&Vs[d * 72 + cc * 8] =
          *(const bf16x8*)&Vh[(size_t)d * T_SEQ + kb * 64 + cc * 8];
    }
    __syncthreads();

    // S = scale * Q K^T   (4 n-tiles x 4 k-chunks)
    f32x4 s[4];
#pragma unroll
    for (int nt = 0; nt < 4; nt++) {
      f32x4 acc = {};
#pragma unroll
      for (int c = 0; c < 4; c++) {
        bf16x8 kf = *(const bf16x8*)&Ks[(nt * 16 + lrow) * 136 + c * 32 + quad * 8];
        acc = __builtin_amdgcn_mfma_f32_16x16x32_bf16(qf[c], kf, acc, 0, 0, 0);
      }
      s[nt] = acc * 0.08838834764831845f;   // 1/sqrt(128)
    }

    if (kb == qb) {  // diagonal block: causal mask
#pragma unroll
      for (int nt = 0; nt < 4; nt++)
#pragma unroll
        for (int r = 0; r < 4; r++) {
          int col = kb * 64 + nt * 16 + lrow;
          int row = q0 + quad * 4 + r;
          if (col > row) s[nt][r] = -1e30f;
        }
    }

    // row max over 64 cols (4 regs locally + 16-lane butterfly)
    float mt[4];
#pragma unroll
    for (int r = 0; r < 4; r++) {
      float v = fmaxf(fmaxf(s[0][r], s[1][r]), fmaxf(s[2][r], s[3][r]));
#pragma unroll
      for (int off = 1; off < 16; off <<= 1) v = fmaxf(v, __shfl_xor(v, off));
      mt[r] = v;
    }
    float alpha[4];
#pragma unroll
    for (int r = 0; r < 4; r++) {
      float mn = fmaxf(m_[r], mt[r]);
      alpha[r] = __expf(m_[r] - mn);
      m_[r] = mn;
    }

    // P = exp(S - m), write to per-wave LDS (C-layout -> A-layout transpose)
    float psum[4];
#pragma unroll
    for (int r = 0; r < 4; r++) psum[r] = 0.f;
#pragma unroll
    for (int nt = 0; nt < 4; nt++)
#pragma unroll
      for (int r = 0; r < 4; r++) {
        float pv = __expf(s[nt][r] - m_[r]);
        psum[r] += pv;
        Ps[wave][(quad * 4 + r) * 72 + nt * 16 + lrow] = (__bf16)pv;
      }
#pragma unroll
    for (int r = 0; r < 4; r++) {
      float v = psum[r];
#pragma unroll
      for (int off = 1; off < 16; off <<= 1) v += __shfl_xor(v, off);
      l_[r] = l_[r] * alpha[r] + v;
    }

    // rescale O accumulators
#pragma unroll
    for (int dt = 0; dt < 8; dt++)
#pragma unroll
      for (int r = 0; r < 4; r++) o[dt][r] *= alpha[r];

    // wave-local LDS write->read ordering
    __asm__ volatile("s_waitcnt lgkmcnt(0)" ::: "memory");

    // O += P V   (8 d-tiles x 2 k-chunks)
    bf16x8 pf[2];
#pragma unroll
    for (int c2 = 0; c2 < 2; c2++)
      pf[c2] = *(const bf16x8*)&Ps[wave][lrow * 72 + c2 * 32 + quad * 8];
#pragma unroll
    for (int dt = 0; dt < 8; dt++)
#pragma unroll
      for (int c2 = 0; c2 < 2; c2++) {
        bf16x8 vf = *(const bf16x8*)&Vs[(dt * 16 + lrow) * 72 + c2 * 32 + quad * 8];
        o[dt] = __builtin_amdgcn_mfma_f32_16x16x32_bf16(pf[c2], vf, o[dt], 0, 0, 0);
      }
  }

  // epilogue: O[b][t][h][d] = o / l
  const int b = bh >> 4, h = bh & 15;
  float inv[4];
#pragma unroll
  for (int r = 0; r < 4; r++) inv[r] = 1.f / l_[r];
#pragma unroll
  for (int dt = 0; dt < 8; dt++)
#pragma unroll
    for (int r = 0; r < 4; r++) {
      int t = q0 + quad * 4 + r;
      size_t idx = (((size_t)b * T_SEQ + t) * NH_ + h) * HD_ + dt * 16 + lrow;
      O[idx] = (__bf16)(o[dt][r] * inv[r]);
    }
}

// ---------------------------------------------------------------------------
// Launcher
// ---------------------------------------------------------------------------
extern "C" void kernel_launch(void* const* d_in, const int* in_sizes, int n_in,
                              void* d_out, int out_size, void* d_ws, size_t ws_size,
                              hipStream_t stream) {
  const float* x      = (const float*)d_in[0];
  const float* w_qkv  = (const float*)d_in[1];
  const float* w_proj = (const float*)d_in[2];
  float* out = (float*)d_out;

  // workspace layout (bytes), with aliasing:
  //   [0,   33.5M)  x16   -> later reused as Q16 (rope output)
  //   [33.5M, 58.7M) w16 (qkv weights bf16)
  //   [58.7M, 67.1M) wp16 (proj weights bf16)
  //   [67.1M, 167.8M) qkv16 -> first 33.5M later reused as O16
  //   [167.8M, 201.3M) K16
  //   [201.3M, 234.9M) Vt16
  char* ws = (char*)d_ws;
  const size_t SZ_X16   = (size_t)B_SZ * T_SEQ * DIM_ * 2;        // 33,554,432
  const size_t SZ_W16   = (size_t)QKVD * DIM_ * 2;                // 25,165,824
  const size_t SZ_WP16  = (size_t)DIM_ * DIM_ * 2;                //  8,388,608
  const size_t SZ_QKV16 = (size_t)B_SZ * T_SEQ * QKVD * 2;        // 100,663,296
  const size_t SZ_HEADS = SZ_X16;                                 // 33,554,432

  __bf16* x16   = (__bf16*)(ws);
  __bf16* w16   = (__bf16*)(ws + SZ_X16);
  __bf16* wp16  = (__bf16*)(ws + SZ_X16 + SZ_W16);
  __bf16* qkv16 = (__bf16*)(ws + SZ_X16 + SZ_W16 + SZ_WP16);
  __bf16* K16   = (__bf16*)(ws + SZ_X16 + SZ_W16 + SZ_WP16 + SZ_QKV16);
  __bf16* Vt16  = (__bf16*)(ws + SZ_X16 + SZ_W16 + SZ_WP16 + SZ_QKV16 + SZ_HEADS);
  __bf16* Q16   = x16;      // alias: x16 dead after QKV GEMM
  __bf16* O16   = qkv16;    // alias: qkv16 dead after rope_split

  const size_t NEED = SZ_X16 + SZ_W16 + SZ_WP16 + SZ_QKV16 + 2 * SZ_HEADS;
  if (ws_size < NEED) return;  // fail visibly rather than corrupt memory

  // 1) casts
  {
    int n4 = (int)((size_t)B_SZ * T_SEQ * DIM_ / 4);
    cast_f32_bf16<<<(n4 + 255) / 256, 256, 0, stream>>>(x, x16, n4);
    n4 = (int)((size_t)QKVD * DIM_ / 4);
    cast_f32_bf16<<<(n4 + 255) / 256, 256, 0, stream>>>(w_qkv, w16, n4);
    n4 = (int)((size_t)DIM_ * DIM_ / 4);
    cast_f32_bf16<<<(n4 + 255) / 256, 256, 0, stream>>>(w_proj, wp16, n4);
  }

  // 2) qkv = x @ w_qkv^T   [8192 x 6144]
  gemm_bt<__bf16><<<dim3(8192 / 128, QKVD / 128), 256, 0, stream>>>(
      x16, w16, qkv16, 8192, QKVD, DIM_);

  // 3) rope + head split (+ V transpose)
  {
    long total = (long)B_SZ * T_SEQ * 3072;   // one thread per element pair
    rope_split<<<(int)(total / 256), 256, 0, stream>>>(qkv16, Q16, K16, Vt16);
  }

  // 4) flash attention -> O16 [b][t][h][d]
  flash_attn<<<dim3(T_SEQ / 64, B_SZ * NH_), 256, 0, stream>>>(Q16, K16, Vt16, O16);

  // 5) out = O @ w_proj^T  [8192 x 2048] fp32
  gemm_bt<float><<<dim3(8192 / 128, DIM_ / 128), 256, 0, stream>>>(
      O16, wp16, out, 8192, DIM_, DIM_);
}

// Round 2
// 998.087 us; speedup vs baseline: 1.2174x; 1.2174x over previous
//
#include <hip/hip_runtime.h>
#include <cstdint>
#include <cstddef>

// ---------------------------------------------------------------------------
// Problem constants
// ---------------------------------------------------------------------------
#define B_SZ   2
#define T_SEQ  4096
#define DIM_   2048
#define NH_    16
#define HD_    128          // head dim
#define QKVD   (3*DIM_)     // 6144
#define SCALE_ 0.08838834764831845f   // 1/sqrt(128)

typedef __bf16 bf16x4 __attribute__((ext_vector_type(4)));
typedef __bf16 bf16x8 __attribute__((ext_vector_type(8)));
typedef float  f32x4  __attribute__((ext_vector_type(4)));

typedef const __attribute__((address_space(1))) void* gas_ptr_t;
typedef       __attribute__((address_space(3))) void* las_ptr_t;

#define GLOAD_LDS16(gp, lp) \
  __builtin_amdgcn_global_load_lds((gas_ptr_t)(gp), (las_ptr_t)(lp), 16, 0, 0)

// ---------------------------------------------------------------------------
// fp32 -> bf16 cast (vectorized, memory bound)
// ---------------------------------------------------------------------------
__global__ void cast_f32_bf16(const float* __restrict__ in,
                              __bf16* __restrict__ out, int n4) {
  int i = blockIdx.x * blockDim.x + threadIdx.x;
  if (i < n4) {
    float4 v = ((const float4*)in)[i];
    bf16x4 o = { (__bf16)v.x, (__bf16)v.y, (__bf16)v.z, (__bf16)v.w };
    ((bf16x4*)out)[i] = o;
  }
}

// ---------------------------------------------------------------------------
// bf16 GEMM, C[m][n] = sum_k A[m][k] * B[n][k]   (B row-major [N][K], i.e. B^T)
// m97 pattern: 128x128 tile, BK=32, global_load_lds width 16, 16x16x32 MFMA.
// ---------------------------------------------------------------------------
__device__ __forceinline__ void store_c(float* C, size_t idx, float v)  { C[idx] = v; }
__device__ __forceinline__ void store_c(__bf16* C, size_t idx, float v) { C[idx] = (__bf16)v; }

template <typename OutT>
__global__ __launch_bounds__(256, 2) void gemm_bt(const __bf16* __restrict__ A,
                                                  const __bf16* __restrict__ B,
                                                  OutT* __restrict__ C,
                                                  int M, int N, int K) {
  __shared__ __attribute__((aligned(16))) __bf16 As[128 * 32];
  __shared__ __attribute__((aligned(16))) __bf16 Bs[128 * 32];

  const int tid  = threadIdx.x;
  const int wave = tid >> 6;
  const int lane = tid & 63;
  const int lrow = lane & 15;
  const int quad = lane >> 4;
  const int m0 = blockIdx.x * 128;
  const int n0 = blockIdx.y * 128;
  const int wm = (wave & 1) * 64;
  const int wn = (wave >> 1) * 64;

  const __bf16* Ag = A + (size_t)(m0 + (tid >> 2)) * K + (tid & 3) * 8;
  const __bf16* Bg = B + (size_t)(n0 + (tid >> 2)) * K + (tid & 3) * 8;

  f32x4 acc[4][4] = {};

  for (int k0 = 0; k0 < K; k0 += 32) {
    __syncthreads();
    GLOAD_LDS16(Ag + k0,                 &As[wave * 16 * 32]);
    GLOAD_LDS16(Ag + k0 + (size_t)64*K,  &As[(64 + wave * 16) * 32]);
    GLOAD_LDS16(Bg + k0,                 &Bs[wave * 16 * 32]);
    GLOAD_LDS16(Bg + k0 + (size_t)64*K,  &Bs[(64 + wave * 16) * 32]);
    __syncthreads();

    bf16x8 a[4], b[4];
#pragma unroll
    for (int i = 0; i < 4; i++)
      a[i] = *(const bf16x8*)&As[(wm + i * 16 + lrow) * 32 + quad * 8];
#pragma unroll
    for (int j = 0; j < 4; j++)
      b[j] = *(const bf16x8*)&Bs[(wn + j * 16 + lrow) * 32 + quad * 8];
#pragma unroll
    for (int i = 0; i < 4; i++)
#pragma unroll
      for (int j = 0; j < 4; j++)
        acc[i][j] = __builtin_amdgcn_mfma_f32_16x16x32_bf16(a[i], b[j], acc[i][j], 0, 0, 0);
  }

#pragma unroll
  for (int i = 0; i < 4; i++)
#pragma unroll
    for (int j = 0; j < 4; j++)
#pragma unroll
      for (int r = 0; r < 4; r++) {
        size_t row = (size_t)(m0 + wm + i * 16 + quad * 4 + r);
        size_t col = (size_t)(n0 + wn + j * 16 + lrow);
        store_c(C, row * (size_t)N + col, acc[i][j][r]);
      }
}

// ---------------------------------------------------------------------------
// RoPE + split heads (unchanged from R0; correct per reference semantics).
//   Q,K: [bh][t][d] bf16 rope'd;  Vt: [bh][d][t] bf16
// ---------------------------------------------------------------------------
__global__ void rope_split(const __bf16* __restrict__ qkv,
                           __bf16* __restrict__ Qo,
                           __bf16* __restrict__ Ko,
                           __bf16* __restrict__ Vt) {
  const long id  = (long)blockIdx.x * blockDim.x + threadIdx.x;
  const int row = (int)(id / 3072);      // b*T + t
  const int p   = (int)(id % 3072);
  const int b = row >> 12;
  const int t = row & (T_SEQ - 1);
  const __bf16* src = qkv + (size_t)row * QKVD;

  if (p < 2048) {
    const bool isq = (p < 1024);
    const int pp = isq ? p : p - 1024;
    const int dp = pp * 2;
    const int h = dp >> 7, d = dp & 127;
    const int base = isq ? 0 : DIM_;
    const float x0 = (float)src[base + dp];
    const float x1 = (float)src[base + dp + 1];
    const int i0 = d & 63, i1 = (d + 1) & 63;
    const float kf = -0.20762050593049014f;   // -log2(10000)/64
    float a0 = (float)t * exp2f(i0 * kf);
    float a1 = (float)t * exp2f(i1 * kf);
    float s0, c0, s1, c1;
    sincosf(a0, &s0, &c0);
    sincosf(a1, &s1, &c1);
    float y0 = x0 * c0 - x1 * s0;
    float y1 = x1 * c1 + x0 * s1;
    __bf16* dst = (isq ? Qo : Ko) + (((size_t)(b * NH_ + h) * T_SEQ + t) * HD_ + d);
    dst[0] = (__bf16)y0;
    dst[1] = (__bf16)y1;
  } else {
    const int dp = (p - 2048) * 2;
    const int h = dp >> 7, d = dp & 127;
    __bf16 v0 = src[2 * DIM_ + dp];
    __bf16 v1 = src[2 * DIM_ + dp + 1];
    size_t base = (size_t)(b * NH_ + h) * HD_;
    Vt[(base + d)     * T_SEQ + t] = v0;
    Vt[(base + d + 1) * T_SEQ + t] = v1;
  }
}

// ---------------------------------------------------------------------------
// Flash attention v2 (causal, online softmax).
// Grid (T/128, B*NH), block 256 = 4 waves. Block owns 128 q rows; wave w owns
// rows [w*32, w*32+32) as two 16-row tiles. K tile = 64 keys/iter.
//
// Computes S^T = K Q^T (A=K-frag, B=Q-frag): C-layout col=lane&15 = q,
// row = quad*4+r = key. Each lane then holds 4 CONSECUTIVE keys per 16x16
// tile at a single q (=lrow):
//   - softmax reduce = local 16 + shfl_xor(16,32)  [2 steps]
//   - P write to A-layout LDS = packed ds_write_b64 (4 bf16/store)
// Next K/V tile prefetched into registers right after the barrier.
// ---------------------------------------------------------------------------
__global__ __launch_bounds__(256, 2) void flash_attn(const __bf16* __restrict__ Q,
                                                     const __bf16* __restrict__ K,
                                                     const __bf16* __restrict__ Vt,
                                                     __bf16* __restrict__ O) {
  __shared__ __attribute__((aligned(16))) __bf16 Ks[64 * 136];
  __shared__ __attribute__((aligned(16))) __bf16 Vs[128 * 72];
  __shared__ __attribute__((aligned(16))) __bf16 Ps[4][32 * 72];

  const int qb   = (gridDim.x - 1) - blockIdx.x;  // heavy blocks dispatch first
  const int bh   = blockIdx.y;
  const int tid  = threadIdx.x;
  const int wave = tid >> 6;
  const int lane = tid & 63;
  const int lrow = lane & 15;
  const int quad = lane >> 4;

  const __bf16* Qh = Q  + (size_t)bh * T_SEQ * HD_;
  const __bf16* Kh = K  + (size_t)bh * T_SEQ * HD_;
  const __bf16* Vh = Vt + (size_t)bh * HD_ * T_SEQ;

  const int q0 = qb * 128;
  const int qw = q0 + wave * 32;          // wave's first q row
  const int kcnt = 2 * qb + 2;            // 64-key tiles to process

  // Q fragments (B-operand layout): 2 q-tiles x 4 d-chunks
  bf16x8 qf[2][4];
#pragma unroll
  for (int qt = 0; qt < 2; qt++)
#pragma unroll
    for (int c = 0; c < 4; c++)
      qf[qt][c] = *(const bf16x8*)&Qh[(size_t)(qw + qt * 16 + lrow) * HD_ + c * 32 + quad * 8];

  f32x4 o[2][8] = {};
  float m_[2] = {-1e30f, -1e30f};
  float l_[2] = {0.f, 0.f};

  // staging coords
  const int krow = tid >> 4, kch = tid & 15;   // K: 16 rows x 16 chunks per step
  const int vrow = tid >> 3, vch = tid & 7;    // V: 32 rows x 8 chunks per step

  bf16x8 kpre[4], vpre[4];
#pragma unroll
  for (int i = 0; i < 4; i++) {
    kpre[i] = *(const bf16x8*)&Kh[(size_t)(i * 16 + krow) * HD_ + kch * 8];
    vpre[i] = *(const bf16x8*)&Vh[(size_t)(i * 32 + vrow) * T_SEQ + vch * 8];
  }

  for (int kb = 0; kb < kcnt; ++kb) {
    __syncthreads();   // prev compute done reading Ks/Vs
#pragma unroll
    for (int i = 0; i < 4; i++) {
      *(bf16x8*)&Ks[(i * 16 + krow) * 136 + kch * 8] = kpre[i];
      *(bf16x8*)&Vs[(i * 32 + vrow) * 72  + vch * 8] = vpre[i];
    }
    __syncthreads();

    // prefetch next tile (overlaps with compute below)
    if (kb + 1 < kcnt) {
      const int nb = (kb + 1) * 64;
#pragma unroll
      for (int i = 0; i < 4; i++) {
        kpre[i] = *(const bf16x8*)&Kh[(size_t)(nb + i * 16 + krow) * HD_ + kch * 8];
        vpre[i] = *(const bf16x8*)&Vh[(size_t)(i * 32 + vrow) * T_SEQ + nb + vch * 8];
      }
    }

    const bool need_mask = (kb * 64 + 63) > qw;   // uniform per wave
    bool act[2];

#pragma unroll
    for (int qt = 0; qt < 2; qt++) {
      const int qbase = qw + qt * 16;             // rows qbase..qbase+15
      act[qt] = (kb * 64) <= (qbase + 15);
      if (!act[qt]) continue;

      // S^T = K Q^T : 4 key-tiles x 4 d-chunks
      f32x4 st[4];
#pragma unroll
      for (int nt = 0; nt < 4; nt++) {
        f32x4 acc = {};
#pragma unroll
        for (int c = 0; c < 4; c++) {
          bf16x8 kf = *(const bf16x8*)&Ks[(nt * 16 + lrow) * 136 + c * 32 + quad * 8];
          acc = __builtin_amdgcn_mfma_f32_16x16x32_bf16(kf, qf[qt][c], acc, 0, 0, 0);
        }
        st[nt] = acc;
      }

      const int qglob = qbase + lrow;
      if (need_mask) {
#pragma unroll
        for (int nt = 0; nt < 4; nt++)
#pragma unroll
          for (int r = 0; r < 4; r++) {
            int key = kb * 64 + nt * 16 + quad * 4 + r;
            if (key > qglob) st[nt][r] = -1e30f;
          }
      }

      // row max (per q = per lrow): local 16 values + 2-step butterfly
      float mt = -1e30f;
#pragma unroll
      for (int nt = 0; nt < 4; nt++)
#pragma unroll
        for (int r = 0; r < 4; r++) mt = fmaxf(mt, st[nt][r]);
      mt = fmaxf(mt, __shfl_xor(mt, 16));
      mt = fmaxf(mt, __shfl_xor(mt, 32));
      const float mnew  = fmaxf(m_[qt], mt);
      const float alpha = __expf((m_[qt] - mnew) * SCALE_);
      m_[qt] = mnew;

      // P = exp((S-m)*scale): packed b64 writes (4 consecutive keys/lane)
      float psum = 0.f;
#pragma unroll
      for (int nt = 0; nt < 4; nt++) {
        bf16x4 pk;
#pragma unroll
        for (int r = 0; r < 4; r++) {
          float pv = __expf((st[nt][r] - mnew) * SCALE_);
          psum += pv;
          pk[r] = (__bf16)pv;
        }
        *(bf16x4*)&Ps[wave][(qt * 16 + lrow) * 72 + nt * 16 + quad * 4] = pk;
      }
      psum += __shfl_xor(psum, 16);
      psum += __shfl_xor(psum, 32);
      l_[qt] = l_[qt] * alpha + psum;

      // rescale O accumulators (alpha broadcast lrow -> quad*4+r)
      float ab[4];
#pragma unroll
      for (int r = 0; r < 4; r++) ab[r] = __shfl(alpha, quad * 4 + r);
#pragma unroll
      for (int dt = 0; dt < 8; dt++)
#pragma unroll
        for (int r = 0; r < 4; r++) o[qt][dt][r] *= ab[r];
    }

    // wave-local: P writes visible to own reads
    __asm__ volatile("s_waitcnt lgkmcnt(0)" ::: "memory");

    // O += P V
#pragma unroll
    for (int qt = 0; qt < 2; qt++) {
      if (!act[qt]) continue;
      bf16x8 pf[2];
#pragma unroll
      for (int c2 = 0; c2 < 2; c2++)
        pf[c2] = *(const bf16x8*)&Ps[wave][(qt * 16 + lrow) * 72 + c2 * 32 + quad * 8];
#pragma unroll
      for (int dt = 0; dt < 8; dt++)
#pragma unroll
        for (int c2 = 0; c2 < 2; c2++) {
          bf16x8 vf = *(const bf16x8*)&Vs[(dt * 16 + lrow) * 72 + c2 * 32 + quad * 8];
          o[qt][dt] = __builtin_amdgcn_mfma_f32_16x16x32_bf16(pf[c2], vf, o[qt][dt], 0, 0, 0);
        }
    }
  }

  // epilogue: O[b][t][h][d] = o / l
  const int b = bh >> 4, h = bh & 15;
#pragma unroll
  for (int qt = 0; qt < 2; qt++) {
    float linv[4];
#pragma unroll
    for (int r = 0; r < 4; r++) linv[r] = 1.f / __shfl(l_[qt], quad * 4 + r);
#pragma unroll
    for (int dt = 0; dt < 8; dt++)
#pragma unroll
      for (int r = 0; r < 4; r++) {
        int t = qw + qt * 16 + quad * 4 + r;
        size_t idx = (((size_t)b * T_SEQ + t) * NH_ + h) * HD_ + dt * 16 + lrow;
        O[idx] = (__bf16)(o[qt][dt][r] * linv[r]);
      }
  }
}

// ---------------------------------------------------------------------------
// Launcher
// ---------------------------------------------------------------------------
extern "C" void kernel_launch(void* const* d_in, const int* in_sizes, int n_in,
                              void* d_out, int out_size, void* d_ws, size_t ws_size,
                              hipStream_t stream) {
  const float* x      = (const float*)d_in[0];
  const float* w_qkv  = (const float*)d_in[1];
  const float* w_proj = (const float*)d_in[2];
  float* out = (float*)d_out;

  char* ws = (char*)d_ws;
  const size_t SZ_X16   = (size_t)B_SZ * T_SEQ * DIM_ * 2;        // 33,554,432
  const size_t SZ_W16   = (size_t)QKVD * DIM_ * 2;                // 25,165,824
  const size_t SZ_WP16  = (size_t)DIM_ * DIM_ * 2;                //  8,388,608
  const size_t SZ_QKV16 = (size_t)B_SZ * T_SEQ * QKVD * 2;        // 100,663,296
  const size_t SZ_HEADS = SZ_X16;

  __bf16* x16   = (__bf16*)(ws);
  __bf16* w16   = (__bf16*)(ws + SZ_X16);
  __bf16* wp16  = (__bf16*)(ws + SZ_X16 + SZ_W16);
  __bf16* qkv16 = (__bf16*)(ws + SZ_X16 + SZ_W16 + SZ_WP16);
  __bf16* K16   = (__bf16*)(ws + SZ_X16 + SZ_W16 + SZ_WP16 + SZ_QKV16);
  __bf16* Vt16  = (__bf16*)(ws + SZ_X16 + SZ_W16 + SZ_WP16 + SZ_QKV16 + SZ_HEADS);
  __bf16* Q16   = x16;      // alias: x16 dead after QKV GEMM
  __bf16* O16   = qkv16;    // alias: qkv16 dead after rope_split

  const size_t NEED = SZ_X16 + SZ_W16 + SZ_WP16 + SZ_QKV16 + 2 * SZ_HEADS;
  if (ws_size < NEED) return;

  // 1) casts
  {
    int n4 = (int)((size_t)B_SZ * T_SEQ * DIM_ / 4);
    cast_f32_bf16<<<(n4 + 255) / 256, 256, 0, stream>>>(x, x16, n4);
    n4 = (int)((size_t)QKVD * DIM_ / 4);
    cast_f32_bf16<<<(n4 + 255) / 256, 256, 0, stream>>>(w_qkv, w16, n4);
    n4 = (int)((size_t)DIM_ * DIM_ / 4);
    cast_f32_bf16<<<(n4 + 255) / 256, 256, 0, stream>>>(w_proj, wp16, n4);
  }

  // 2) qkv = x @ w_qkv^T   [8192 x 6144]
  gemm_bt<__bf16><<<dim3(8192 / 128, QKVD / 128), 256, 0, stream>>>(
      x16, w16, qkv16, 8192, QKVD, DIM_);

  // 3) rope + head split (+ V transpose)
  {
    long total = (long)B_SZ * T_SEQ * 3072;
    rope_split<<<(int)(total / 256), 256, 0, stream>>>(qkv16, Q16, K16, Vt16);
  }

  // 4) flash attention -> O16 [b][t][h][d]
  flash_attn<<<dim3(T_SEQ / 128, B_SZ * NH_), 256, 0, stream>>>(Q16, K16, Vt16, O16);

  // 5) out = O @ w_proj^T  [8192 x 2048] fp32
  gemm_bt<float><<<dim3(8192 / 128, DIM_ / 128), 256, 0, stream>>>(
      O16, wp16, out, 8192, DIM_, DIM_);
}

// Round 4
// 928.831 us; speedup vs baseline: 1.3082x; 1.0746x over previous
//
#include <hip/hip_runtime.h>
#include <cstdint>
#include <cstddef>

// ---------------------------------------------------------------------------
// Problem constants
// ---------------------------------------------------------------------------
#define B_SZ   2
#define T_SEQ  4096
#define DIM_   2048
#define NH_    16
#define HD_    128          // head dim
#define QKVD   (3*DIM_)     // 6144
#define SCALE_ 0.08838834764831845f   // 1/sqrt(128)

typedef __bf16 bf16x4 __attribute__((ext_vector_type(4)));
typedef __bf16 bf16x8 __attribute__((ext_vector_type(8)));
typedef float  f32x4  __attribute__((ext_vector_type(4)));

typedef const __attribute__((address_space(1))) void* gas_ptr_t;
typedef       __attribute__((address_space(3))) void* las_ptr_t;

#define GLOAD_LDS16(gp, lp) \
  __builtin_amdgcn_global_load_lds((gas_ptr_t)(gp), (las_ptr_t)(lp), 16, 0, 0)

// ---------------------------------------------------------------------------
// fp32 -> bf16 cast
// ---------------------------------------------------------------------------
__global__ void cast_f32_bf16(const float* __restrict__ in,
                              __bf16* __restrict__ out, int n4) {
  int i = blockIdx.x * blockDim.x + threadIdx.x;
  if (i < n4) {
    float4 v = ((const float4*)in)[i];
    bf16x4 o = { (__bf16)v.x, (__bf16)v.y, (__bf16)v.z, (__bf16)v.w };
    ((bf16x4*)out)[i] = o;
  }
}

// ---------------------------------------------------------------------------
// bf16 GEMM (m97 pattern) — unchanged, known-good ~900 TF structure.
// ---------------------------------------------------------------------------
__device__ __forceinline__ void store_c(float* C, size_t idx, float v)  { C[idx] = v; }
__device__ __forceinline__ void store_c(__bf16* C, size_t idx, float v) { C[idx] = (__bf16)v; }

template <typename OutT>
__global__ __launch_bounds__(256, 2) void gemm_bt(const __bf16* __restrict__ A,
                                                  const __bf16* __restrict__ B,
                                                  OutT* __restrict__ C,
                                                  int M, int N, int K) {
  __shared__ __attribute__((aligned(16))) __bf16 As[128 * 32];
  __shared__ __attribute__((aligned(16))) __bf16 Bs[128 * 32];

  const int tid  = threadIdx.x;
  const int wave = tid >> 6;
  const int lane = tid & 63;
  const int lrow = lane & 15;
  const int quad = lane >> 4;
  const int m0 = blockIdx.x * 128;
  const int n0 = blockIdx.y * 128;
  const int wm = (wave & 1) * 64;
  const int wn = (wave >> 1) * 64;

  const __bf16* Ag = A + (size_t)(m0 + (tid >> 2)) * K + (tid & 3) * 8;
  const __bf16* Bg = B + (size_t)(n0 + (tid >> 2)) * K + (tid & 3) * 8;

  f32x4 acc[4][4] = {};

  for (int k0 = 0; k0 < K; k0 += 32) {
    __syncthreads();
    GLOAD_LDS16(Ag + k0,                 &As[wave * 16 * 32]);
    GLOAD_LDS16(Ag + k0 + (size_t)64*K,  &As[(64 + wave * 16) * 32]);
    GLOAD_LDS16(Bg + k0,                 &Bs[wave * 16 * 32]);
    GLOAD_LDS16(Bg + k0 + (size_t)64*K,  &Bs[(64 + wave * 16) * 32]);
    __syncthreads();

    bf16x8 a[4], b[4];
#pragma unroll
    for (int i = 0; i < 4; i++)
      a[i] = *(const bf16x8*)&As[(wm + i * 16 + lrow) * 32 + quad * 8];
#pragma unroll
    for (int j = 0; j < 4; j++)
      b[j] = *(const bf16x8*)&Bs[(wn + j * 16 + lrow) * 32 + quad * 8];
#pragma unroll
    for (int i = 0; i < 4; i++)
#pragma unroll
      for (int j = 0; j < 4; j++)
        acc[i][j] = __builtin_amdgcn_mfma_f32_16x16x32_bf16(a[i], b[j], acc[i][j], 0, 0, 0);
  }

#pragma unroll
  for (int i = 0; i < 4; i++)
#pragma unroll
    for (int j = 0; j < 4; j++)
#pragma unroll
      for (int r = 0; r < 4; r++) {
        size_t row = (size_t)(m0 + wm + i * 16 + quad * 4 + r);
        size_t col = (size_t)(n0 + wn + j * 16 + lrow);
        store_c(C, row * (size_t)N + col, acc[i][j][r]);
      }
}

// ---------------------------------------------------------------------------
// RoPE + split heads. Q,K: [bh][t][d] rope'd; Vt: [bh][d][t].
// ---------------------------------------------------------------------------
__global__ void rope_split(const __bf16* __restrict__ qkv,
                           __bf16* __restrict__ Qo,
                           __bf16* __restrict__ Ko,
                           __bf16* __restrict__ Vt) {
  const long id  = (long)blockIdx.x * blockDim.x + threadIdx.x;
  const int row = (int)(id / 3072);      // b*T + t
  const int p   = (int)(id % 3072);
  const int b = row >> 12;
  const int t = row & (T_SEQ - 1);
  const __bf16* src = qkv + (size_t)row * QKVD;

  if (p < 2048) {
    const bool isq = (p < 1024);
    const int pp = isq ? p : p - 1024;
    const int dp = pp * 2;
    const int h = dp >> 7, d = dp & 127;
    const int base = isq ? 0 : DIM_;
    const float x0 = (float)src[base + dp];
    const float x1 = (float)src[base + dp + 1];
    const int i0 = d & 63, i1 = (d + 1) & 63;
    const float kf = -0.20762050593049014f;   // -log2(10000)/64
    float a0 = (float)t * exp2f(i0 * kf);
    float a1 = (float)t * exp2f(i1 * kf);
    float s0, c0, s1, c1;
    sincosf(a0, &s0, &c0);
    sincosf(a1, &s1, &c1);
    float y0 = x0 * c0 - x1 * s0;
    float y1 = x1 * c1 + x0 * s1;
    __bf16* dst = (isq ? Qo : Ko) + (((size_t)(b * NH_ + h) * T_SEQ + t) * HD_ + d);
    dst[0] = (__bf16)y0;
    dst[1] = (__bf16)y1;
  } else {
    const int dp = (p - 2048) * 2;
    const int h = dp >> 7, d = dp & 127;
    __bf16 v0 = src[2 * DIM_ + dp];
    __bf16 v1 = src[2 * DIM_ + dp + 1];
    size_t base = (size_t)(b * NH_ + h) * HD_;
    Vt[(base + d)     * T_SEQ + t] = v0;
    Vt[(base + d + 1) * T_SEQ + t] = v1;
  }
}

// ---------------------------------------------------------------------------
// Flash attention v3 (fixed): 128 q/block (32 q/wave as 2x16), 64 keys/iter,
// double-buffered K/V LDS + register prefetch => ONE barrier per iteration.
// XOR-swizzled LDS (16B chunks, c ^= row&7) => zero padding, conflict-free.
// R3 bug was here: QK^T chunk index must be kc*4+quad (was kc*8+quad,
// reading past the 16-chunk K row for kc>=2).
// ---------------------------------------------------------------------------
__global__ __launch_bounds__(256, 2) void flash_attn(const __bf16* __restrict__ Q,
                                                     const __bf16* __restrict__ K,
                                                     const __bf16* __restrict__ Vt,
                                                     __bf16* __restrict__ O) {
  __shared__ __attribute__((aligned(16))) __bf16 Ks[2][64 * 128];
  __shared__ __attribute__((aligned(16))) __bf16 Vs[2][128 * 64];
  __shared__ __attribute__((aligned(16))) __bf16 Ps[4][32 * 64];

  const int qb   = (gridDim.x - 1) - blockIdx.x;  // heavy blocks dispatch first
  const int bh   = blockIdx.y;
  const int tid  = threadIdx.x;
  const int wave = tid >> 6;
  const int lane = tid & 63;
  const int l15  = lane & 15;
  const int quad = lane >> 4;

  const __bf16* Qh = Q  + (size_t)bh * T_SEQ * HD_;
  const __bf16* Kh = K  + (size_t)bh * T_SEQ * HD_;
  const __bf16* Vh = Vt + (size_t)bh * HD_ * T_SEQ;

  const int qw   = qb * 128 + wave * 32;   // wave's first q row
  const int kcnt = 2 * qb + 2;             // 64-key tiles

  // Q fragments (B-operand): 2 q-tiles x 4 d-chunks (32 VGPR)
  bf16x8 qf[2][4];
#pragma unroll
  for (int qt = 0; qt < 2; qt++)
#pragma unroll
    for (int kc = 0; kc < 4; kc++)
      qf[qt][kc] = *(const bf16x8*)&Qh[(size_t)(qw + qt * 16 + l15) * HD_ + kc * 32 + quad * 8];

  f32x4 o[2][8] = {};
  float m_[2] = {-1e30f, -1e30f};
  float l_[2] = {0.f, 0.f};

  // staging coords: K 64 rows x 16 chunks (4 thr/row); V 128 rows x 8 chunks (2 thr/row)
  const int krow = tid >> 2, kq4 = tid & 3;
  const int vrow = tid >> 1, vh2 = tid & 1;

  bf16x8 kpre[4], vpre[4];

#define LOAD_TILES(KB)                                                          \
  {                                                                             \
    const __bf16* kg = Kh + (size_t)((KB) * 64 + krow) * HD_;                   \
    const __bf16* vg = Vh + (size_t)vrow * T_SEQ + (KB) * 64;                   \
    _Pragma("unroll")                                                           \
    for (int j = 0; j < 4; j++) {                                               \
      kpre[j] = *(const bf16x8*)&kg[(j * 4 + kq4) * 8];                         \
      vpre[j] = *(const bf16x8*)&vg[(vh2 * 4 + j) * 8];                         \
    }                                                                           \
  }

#define STORE_TILES(BUF)                                                        \
  {                                                                             \
    _Pragma("unroll")                                                           \
    for (int j = 0; j < 4; j++) {                                               \
      int kc_ = (j * 4 + kq4) ^ (krow & 7);                                     \
      *(bf16x8*)&Ks[BUF][krow * 128 + kc_ * 8] = kpre[j];                       \
      int vc_ = (vh2 * 4 + j) ^ (vrow & 7);                                     \
      *(bf16x8*)&Vs[BUF][vrow * 64 + vc_ * 8] = vpre[j];                        \
    }                                                                           \
  }

  LOAD_TILES(0);
  STORE_TILES(0);
  if (kcnt > 1) LOAD_TILES(1);
  __syncthreads();

  for (int kb = 0; kb < kcnt; ++kb) {
    const int cur = kb & 1;
    // stage tile kb+1 into the other buffer (its last readers finished
    // at compute(kb-1), guarded by the barrier at the bottom of kb-1)
    if (kb + 1 < kcnt) STORE_TILES((kb + 1) & 1);
    if (kb + 2 < kcnt) LOAD_TILES(kb + 2);

    if (kb * 64 <= qw + 31) {   // wave has >=1 unmasked key this tile
      // ---- S^T = K Q^T : kf shared across both q-tiles ----
      f32x4 st[2][4];
#pragma unroll
      for (int kt = 0; kt < 4; kt++) {
        f32x4 a0 = {}, a1 = {};
        const int row = kt * 16 + l15;
#pragma unroll
        for (int kc = 0; kc < 4; kc++) {
          const int c = kc * 4 + quad;                 // chunk = (kc*32+quad*8)/8
          bf16x8 kf = *(const bf16x8*)&Ks[cur][row * 128 + (c ^ (row & 7)) * 8];
          a0 = __builtin_amdgcn_mfma_f32_16x16x32_bf16(kf, qf[0][kc], a0, 0, 0, 0);
          a1 = __builtin_amdgcn_mfma_f32_16x16x32_bf16(kf, qf[1][kc], a1, 0, 0, 0);
        }
        st[0][kt] = a0; st[1][kt] = a1;
      }

      // ---- causal mask (diagonal region only) ----
      if (kb * 64 + 63 > qw) {
#pragma unroll
        for (int qt = 0; qt < 2; qt++)
#pragma unroll
          for (int kt = 0; kt < 4; kt++)
#pragma unroll
            for (int r = 0; r < 4; r++) {
              int key = kb * 64 + kt * 16 + quad * 4 + r;
              int q   = qw + qt * 16 + l15;
              if (key > q) st[qt][kt][r] = -1e30f;
            }
      }

      // ---- online softmax + P write (per q-tile) ----
      float alpha[2];
#pragma unroll
      for (int qt = 0; qt < 2; qt++) {
        float mt = -1e30f;
#pragma unroll
        for (int kt = 0; kt < 4; kt++)
#pragma unroll
          for (int r = 0; r < 4; r++) mt = fmaxf(mt, st[qt][kt][r]);
        mt = fmaxf(mt, __shfl_xor(mt, 16));
        mt = fmaxf(mt, __shfl_xor(mt, 32));
        const float mnew = fmaxf(m_[qt], mt);
        alpha[qt] = __expf((m_[qt] - mnew) * SCALE_);
        m_[qt] = mnew;

        float ps = 0.f;
        const int prow = qt * 16 + l15;
#pragma unroll
        for (int kt = 0; kt < 4; kt++) {
          bf16x4 pk;
#pragma unroll
          for (int r = 0; r < 4; r++) {
            float pv = __expf((st[qt][kt][r] - mnew) * SCALE_);
            ps += pv;
            pk[r] = (__bf16)pv;
          }
          const int ec = kt * 16 + quad * 4;           // element col in [0,64)
          const int c  = (ec >> 3) ^ (prow & 7);       // swizzled 16B chunk
          *(bf16x4*)&Ps[wave][prow * 64 + c * 8 + (ec & 7)] = pk;
        }
        ps += __shfl_xor(ps, 16);
        ps += __shfl_xor(ps, 32);
        l_[qt] = l_[qt] * alpha[qt] + ps;
      }

      // per-wave LDS write->read ordering for Ps
      __asm__ volatile("s_waitcnt lgkmcnt(0)" ::: "memory");

      // ---- rescale O ----
#pragma unroll
      for (int qt = 0; qt < 2; qt++)
#pragma unroll
        for (int r = 0; r < 4; r++) {
          float a = __shfl(alpha[qt], quad * 4 + r);
#pragma unroll
          for (int dt = 0; dt < 8; dt++) o[qt][dt][r] *= a;
        }

      // ---- O += P V : vf shared across both q-tiles ----
#pragma unroll
      for (int kc2 = 0; kc2 < 2; kc2++) {
        const int ec = kc2 * 32 + quad * 8;
        const int pc = (ec >> 3) ^ (l15 & 7);          // (qt*16+l15)&7 == l15&7
        bf16x8 pf0 = *(const bf16x8*)&Ps[wave][(l15)      * 64 + pc * 8];
        bf16x8 pf1 = *(const bf16x8*)&Ps[wave][(16 + l15) * 64 + pc * 8];
#pragma unroll
        for (int dt = 0; dt < 8; dt++) {
          const int vr = dt * 16 + l15;
          const int vc = (ec >> 3) ^ (vr & 7);
          bf16x8 vf = *(const bf16x8*)&Vs[cur][vr * 64 + vc * 8];
          o[0][dt] = __builtin_amdgcn_mfma_f32_16x16x32_bf16(pf0, vf, o[0][dt], 0, 0, 0);
          o[1][dt] = __builtin_amdgcn_mfma_f32_16x16x32_bf16(pf1, vf, o[1][dt], 0, 0, 0);
        }
      }
    }
    __syncthreads();   // tile kb fully consumed; tile kb+1 writes visible
  }

  // ---- epilogue: O[b][t][h][d] = o / l ----
  const int b = bh >> 4, h = bh & 15;
#pragma unroll
  for (int qt = 0; qt < 2; qt++) {
    float il = 1.f / l_[qt];
#pragma unroll
    for (int r = 0; r < 4; r++) {
      float linv = __shfl(il, quad * 4 + r);
      int t = qw + qt * 16 + quad * 4 + r;
#pragma unroll
      for (int dt = 0; dt < 8; dt++) {
        size_t idx = (((size_t)b * T_SEQ + t) * NH_ + h) * HD_ + dt * 16 + l15;
        O[idx] = (__bf16)(o[qt][dt][r] * linv);
      }
    }
  }
}

// ---------------------------------------------------------------------------
// Launcher
// ---------------------------------------------------------------------------
extern "C" void kernel_launch(void* const* d_in, const int* in_sizes, int n_in,
                              void* d_out, int out_size, void* d_ws, size_t ws_size,
                              hipStream_t stream) {
  const float* x      = (const float*)d_in[0];
  const float* w_qkv  = (const float*)d_in[1];
  const float* w_proj = (const float*)d_in[2];
  float* out = (float*)d_out;

  char* ws = (char*)d_ws;
  const size_t SZ_X16   = (size_t)B_SZ * T_SEQ * DIM_ * 2;        // 33,554,432
  const size_t SZ_W16   = (size_t)QKVD * DIM_ * 2;                // 25,165,824
  const size_t SZ_WP16  = (size_t)DIM_ * DIM_ * 2;                //  8,388,608
  const size_t SZ_QKV16 = (size_t)B_SZ * T_SEQ * QKVD * 2;        // 100,663,296
  const size_t SZ_HEADS = SZ_X16;

  __bf16* x16   = (__bf16*)(ws);
  __bf16* w16   = (__bf16*)(ws + SZ_X16);
  __bf16* wp16  = (__bf16*)(ws + SZ_X16 + SZ_W16);
  __bf16* qkv16 = (__bf16*)(ws + SZ_X16 + SZ_W16 + SZ_WP16);
  __bf16* K16   = (__bf16*)(ws + SZ_X16 + SZ_W16 + SZ_WP16 + SZ_QKV16);
  __bf16* Vt16  = (__bf16*)(ws + SZ_X16 + SZ_W16 + SZ_WP16 + SZ_QKV16 + SZ_HEADS);
  __bf16* Q16   = x16;      // alias: x16 dead after QKV GEMM
  __bf16* O16   = qkv16;    // alias: qkv16 dead after rope_split

  const size_t NEED = SZ_X16 + SZ_W16 + SZ_WP16 + SZ_QKV16 + 2 * SZ_HEADS;
  if (ws_size < NEED) return;

  // 1) casts
  {
    int n4 = (int)((size_t)B_SZ * T_SEQ * DIM_ / 4);
    cast_f32_bf16<<<(n4 + 255) / 256, 256, 0, stream>>>(x, x16, n4);
    n4 = (int)((size_t)QKVD * DIM_ / 4);
    cast_f32_bf16<<<(n4 + 255) / 256, 256, 0, stream>>>(w_qkv, w16, n4);
    n4 = (int)((size_t)DIM_ * DIM_ / 4);
    cast_f32_bf16<<<(n4 + 255) / 256, 256, 0, stream>>>(w_proj, wp16, n4);
  }

  // 2) qkv = x @ w_qkv^T   [8192 x 6144]
  gemm_bt<__bf16><<<dim3(8192 / 128, QKVD / 128), 256, 0, stream>>>(
      x16, w16, qkv16, 8192, QKVD, DIM_);

  // 3) rope + head split (+ V transpose)
  {
    long total = (long)B_SZ * T_SEQ * 3072;
    rope_split<<<(int)(total / 256), 256, 0, stream>>>(qkv16, Q16, K16, Vt16);
  }

  // 4) flash attention -> O16 [b][t][h][d]
  flash_attn<<<dim3(T_SEQ / 128, B_SZ * NH_), 256, 0, stream>>>(Q16, K16, Vt16, O16);

  // 5) out = O @ w_proj^T  [8192 x 2048] fp32
  gemm_bt<float><<<dim3(8192 / 128, DIM_ / 128), 256, 0, stream>>>(
      O16, wp16, out, 8192, DIM_, DIM_);
}